// Round 2
// baseline (1069.482 us; speedup 1.0000x reference)
//
#include <hip/hip_runtime.h>
#include <hip/hip_bf16.h>

// Problem dims
#define NB 128      // batch B
#define NA 512      // attention positions A
#define NR 512      // R == IN
#define NOUT 10000

typedef __attribute__((ext_vector_type(8))) short bf16x8;
typedef __attribute__((ext_vector_type(4))) float f32x4;

__device__ inline short f2bf(float f) {
  __hip_bfloat16 h = __float2bfloat16(f);
  return *reinterpret_cast<const short*>(&h);
}
__device__ inline float bf2f(short s) {
  unsigned u = (unsigned)(unsigned short)s << 16;
  return __uint_as_float(u);
}
__device__ inline float fast_tanh(float x) {
  float e = __expf(2.0f * x);
  return 1.0f - 2.0f / (e + 1.0f);
}
__device__ inline float fast_sigmoid(float x) {
  return 1.0f / (1.0f + __expf(-x));
}

// fp32 -> bf16 bulk convert, 8 elems/thread
__global__ __launch_bounds__(256) void cvt_f2b(
    const float* __restrict__ src, short* __restrict__ dst, int n8)
{
  const int i = blockIdx.x * 256 + threadIdx.x;
  if (i >= n8) return;
  f32x4 a = ((const f32x4*)src)[2 * i];
  f32x4 b = ((const f32x4*)src)[2 * i + 1];
  bf16x8 r;
  r[0] = f2bf(a[0]); r[1] = f2bf(a[1]); r[2] = f2bf(a[2]); r[3] = f2bf(a[3]);
  r[4] = f2bf(b[0]); r[5] = f2bf(b[1]); r[6] = f2bf(b[2]); r[7] = f2bf(b[3]);
  ((bf16x8*)dst)[i] = r;
}

// ---------------------------------------------------------------------------
// score_pass: fused v = att@Wa^T (+ba) ; scores = sum_k tanh(v+hh)*Wd.
// All-bf16 inputs, register-resident, no LDS tiles, no barriers in K loop.
// Block 512 thr = 8 waves; wave tile M=64 (k_out), block N=64 att rows.
// ---------------------------------------------------------------------------
__global__ __launch_bounds__(512, 4) void score_pass(
    const short* __restrict__ attb,  // [B*A][R] bf16
    const short* __restrict__ Wk,    // [A][R] bf16
    const float* __restrict__ ba,    // [A]
    const float* __restrict__ Wd,    // [A]
    const float* __restrict__ hh1,   // [B*A]
    const float* __restrict__ hh2,   // may be null
    float* __restrict__ sc1,         // [B*A]
    float* __restrict__ sc2)         // may be null
{
  __shared__ float sred[8][4][16][2];
  const int tid = threadIdx.x;
  const int wv = tid >> 6;
  const int lane = tid & 63;
  const int l15 = lane & 15, l4 = lane >> 4;
  const int row0 = blockIdx.x * 64;        // att-row base (N)
  const int mrow0 = wv * 64;               // k_out base for this wave (M)
  const bool has2 = (hh2 != nullptr);

  f32x4 acc[4][4] = {};
  const short* ap = Wk + (size_t)(mrow0 + l15) * 512 + l4 * 8;
  const short* bp = attb + (size_t)(row0 + l15) * 512 + l4 * 8;

#pragma unroll 2
  for (int kk = 0; kk < 512; kk += 32) {
    bf16x8 afr[4], bfr[4];
#pragma unroll
    for (int mf = 0; mf < 4; mf++)
      afr[mf] = *(const bf16x8*)(ap + mf * 16 * 512 + kk);
#pragma unroll
    for (int nf = 0; nf < 4; nf++)
      bfr[nf] = *(const bf16x8*)(bp + (size_t)nf * 16 * 512 + kk);
#pragma unroll
    for (int mf = 0; mf < 4; mf++)
#pragma unroll
      for (int nf = 0; nf < 4; nf++)
        acc[mf][nf] = __builtin_amdgcn_mfma_f32_16x16x32_bf16(afr[mf], bfr[nf], acc[mf][nf], 0, 0, 0);
  }

  // epilogue: scores[col] = sum_k tanh(v + hh[col]) * Wd[k]
  float h1v[4], h2v[4];
#pragma unroll
  for (int nf = 0; nf < 4; nf++) {
    const int colg = row0 + nf * 16 + l15;   // == b*512 + a
    h1v[nf] = hh1[colg];
    h2v[nf] = has2 ? hh2[colg] : 0.f;
  }
  float p1[4] = {0, 0, 0, 0}, p2[4] = {0, 0, 0, 0};
#pragma unroll
  for (int mf = 0; mf < 4; mf++) {
#pragma unroll
    for (int r = 0; r < 4; r++) {
      const int krow = mrow0 + mf * 16 + l4 * 4 + r;
      const float bav = ba[krow];
      const float wdv = Wd[krow];
#pragma unroll
      for (int nf = 0; nf < 4; nf++) {
        const float v = acc[mf][nf][r] + bav;
        p1[nf] += fast_tanh(v + h1v[nf]) * wdv;
        if (has2) p2[nf] += fast_tanh(v + h2v[nf]) * wdv;
      }
    }
  }
#pragma unroll
  for (int nf = 0; nf < 4; nf++) {
    float x1 = p1[nf];
    x1 += __shfl_xor(x1, 16); x1 += __shfl_xor(x1, 32);
    float x2 = p2[nf];
    x2 += __shfl_xor(x2, 16); x2 += __shfl_xor(x2, 32);
    if (l4 == 0) { sred[wv][nf][l15][0] = x1; sred[wv][nf][l15][1] = x2; }
  }
  __syncthreads();
  if (tid < 128) {
    const int v2 = tid >> 6, nf = (tid >> 4) & 3, c = tid & 15;
    if (v2 == 0 || has2) {
      float s = 0.f;
#pragma unroll
      for (int w = 0; w < 8; w++) s += sred[w][nf][c][v2];
      float* dst = v2 ? sc2 : sc1;
      dst[row0 + nf * 16 + c] = s;
    }
  }
}

// ---------------------------------------------------------------------------
// Generic GEMM: out[n][m] = sum_k A[m][k]*B[n][k] + bias[m], A/B bf16 [.][512]
// Block: 256 thr (4 waves along M, wave tile 64x32). grid = (ceil(M/256), N/32)
// ---------------------------------------------------------------------------
__global__ __launch_bounds__(256) void gemm_tn512(
    const short* __restrict__ Ab, const short* __restrict__ Bb,
    const float* __restrict__ bias, float* __restrict__ out,
    const int M, const int Mclamp)
{
  const int tid = threadIdx.x;
  const int wv = tid >> 6, lane = tid & 63;
  const int l15 = lane & 15, l4 = lane >> 4;
  const int mrow0 = blockIdx.x * 256 + wv * 64;
  const int ncol0 = blockIdx.y * 32;
  f32x4 acc[4][2] = {};
  for (int kk = 0; kk < 512; kk += 32) {
    bf16x8 afr[4];
#pragma unroll
    for (int mf = 0; mf < 4; mf++) {
      int row = mrow0 + mf * 16 + l15;
      row = row > Mclamp ? Mclamp : row;
      afr[mf] = *(const bf16x8*)(Ab + (size_t)row * 512 + kk + l4 * 8);
    }
    bf16x8 bfr[2];
#pragma unroll
    for (int nf = 0; nf < 2; nf++)
      bfr[nf] = *(const bf16x8*)(Bb + (size_t)(ncol0 + nf * 16 + l15) * 512 + kk + l4 * 8);
#pragma unroll
    for (int mf = 0; mf < 4; mf++)
#pragma unroll
      for (int nf = 0; nf < 2; nf++)
        acc[mf][nf] = __builtin_amdgcn_mfma_f32_16x16x32_bf16(afr[mf], bfr[nf], acc[mf][nf], 0, 0, 0);
  }
#pragma unroll
  for (int mf = 0; mf < 4; mf++)
#pragma unroll
    for (int r = 0; r < 4; r++) {
      const int row = mrow0 + mf * 16 + l4 * 4 + r;
      if (row < M) {
        const float bv = bias ? bias[row] : 0.f;
#pragma unroll
        for (int nf = 0; nf < 2; nf++) {
          const int col = ncol0 + nf * 16 + l15;
          out[(size_t)col * M + row] = acc[mf][nf][r] + bv;
        }
      }
    }
}

// ---------------------------------------------------------------------------
// LSTM gates GEMM: sums[b][n] = xt@i2h[n] + prev_h@h2h[n] + ar@a2h[n] + biases
// M=4096, N=128, K=3*512, all operands bf16.
// ---------------------------------------------------------------------------
__global__ __launch_bounds__(256) void gates_gemm(
    const short* __restrict__ A1, const short* __restrict__ A2, const short* __restrict__ A3,
    const short* __restrict__ B1, const short* __restrict__ B2, const short* __restrict__ B3,
    const float* __restrict__ b1, const float* __restrict__ b2, const float* __restrict__ b3,
    float* __restrict__ out)
{
  const int tid = threadIdx.x;
  const int wv = tid >> 6, lane = tid & 63;
  const int l15 = lane & 15, l4 = lane >> 4;
  const int mrow0 = blockIdx.x * 256 + wv * 64;
  const int ncol0 = blockIdx.y * 32;
  f32x4 acc[4][2] = {};
#pragma unroll 1
  for (int seg = 0; seg < 3; seg++) {
    const short* As = seg == 0 ? A1 : (seg == 1 ? A2 : A3);
    const short* Bs = seg == 0 ? B1 : (seg == 1 ? B2 : B3);
    for (int kk = 0; kk < 512; kk += 32) {
      bf16x8 afr[4];
#pragma unroll
      for (int mf = 0; mf < 4; mf++)
        afr[mf] = *(const bf16x8*)(As + (size_t)(mrow0 + mf * 16 + l15) * 512 + kk + l4 * 8);
      bf16x8 bfr[2];
#pragma unroll
      for (int nf = 0; nf < 2; nf++)
        bfr[nf] = *(const bf16x8*)(Bs + (size_t)(ncol0 + nf * 16 + l15) * 512 + kk + l4 * 8);
#pragma unroll
      for (int mf = 0; mf < 4; mf++)
#pragma unroll
        for (int nf = 0; nf < 2; nf++)
          acc[mf][nf] = __builtin_amdgcn_mfma_f32_16x16x32_bf16(afr[mf], bfr[nf], acc[mf][nf], 0, 0, 0);
    }
  }
#pragma unroll
  for (int mf = 0; mf < 4; mf++)
#pragma unroll
    for (int r = 0; r < 4; r++) {
      const int row = mrow0 + mf * 16 + l4 * 4 + r;
      const float bv = b1[row] + b2[row] + b3[row];
#pragma unroll
      for (int nf = 0; nf < 2; nf++) {
        const int col = ncol0 + nf * 16 + l15;
        out[(size_t)col * 4096 + row] = acc[mf][nf][r] + bv;
      }
    }
}

// softmax over rows of 512 (in place)
__global__ __launch_bounds__(512) void softmax512(float* __restrict__ d)
{
  const int row = blockIdx.x, t = threadIdx.x;
  const int lane = t & 63, wv = t >> 6;
  __shared__ float red[8];
  float x = d[(size_t)row * 512 + t];
  float m = x;
#pragma unroll
  for (int o = 32; o >= 1; o >>= 1) m = fmaxf(m, __shfl_xor(m, o));
  if (lane == 0) red[wv] = m;
  __syncthreads();
  float gm = red[0];
#pragma unroll
  for (int i = 1; i < 8; i++) gm = fmaxf(gm, red[i]);
  const float e = __expf(x - gm);
  float s = e;
#pragma unroll
  for (int o = 32; o >= 1; o >>= 1) s += __shfl_xor(s, o);
  __syncthreads();
  if (lane == 0) red[wv] = s;
  __syncthreads();
  float gs = 0.f;
#pragma unroll
  for (int i = 0; i < 8; i++) gs += red[i];
  d[(size_t)row * 512 + t] = e / gs;
}

// att_res[b][r] = sum_a att[b][a][r] * w[b][a]  (bf16 att, 4 a-chunks, atomic)
__global__ __launch_bounds__(512) void att_res_pass(
    const short* __restrict__ attb,
    const float* __restrict__ w1, const float* __restrict__ w2,
    float* __restrict__ ar1, float* __restrict__ ar2)
{
  const int r = threadIdx.x;
  const int chunk = blockIdx.x;
  const int b = blockIdx.y;
  const bool has2 = (w2 != nullptr);
  float a1 = 0.f, a2 = 0.f;
  const int abase = chunk * 128;
  for (int a = 0; a < 128; a++) {
    const int ai = abase + a;
    const float x = bf2f(attb[((size_t)b * 512 + ai) * 512 + r]);
    a1 += x * w1[b * 512 + ai];
    if (has2) a2 += x * w2[b * 512 + ai];
  }
  atomicAdd(&ar1[b * 512 + r], a1);
  if (has2) atomicAdd(&ar2[b * 512 + r], a2);
}

// gate nonlinearities + per-p LSTM cell + mean over P
__global__ __launch_bounds__(256) void lstm_combine(
    const float* __restrict__ sums, const float* __restrict__ prev_c,
    float* __restrict__ out_c, float* __restrict__ nh_f, short* __restrict__ nh_bf)
{
  const int idx = blockIdx.x * 256 + threadIdx.x;   // 65536
  const int b = idx >> 9, r = idx & 511;
  const float* sb = sums + (size_t)b * 4096;
  const float pc = prev_c[idx];
  float nc = 0.f, nh = 0.f;
#pragma unroll
  for (int p = 0; p < 2; p++) {
    const float si = sb[p * 2048 + r];
    const float sf = sb[p * 2048 + 512 + r];
    const float so = sb[p * 2048 + 1024 + r];
    const float st = sb[p * 2048 + 1536 + r];
    const float ig = fast_sigmoid(si), fg = fast_sigmoid(sf), og = fast_sigmoid(so);
    const float it = fast_tanh(st);
    const float c = fg * pc + ig * it;
    const float h = og * fast_tanh(c);
    nc += c; nh += h;
  }
  nc *= 0.5f; nh *= 0.5f;
  out_c[idx] = nc;
  nh_f[idx] = nh;
  nh_bf[idx] = f2bf(nh);
}

// out_f = a + b (fp32); optional bf16 copy
__global__ __launch_bounds__(256) void add_store(
    const float* __restrict__ a, const float* __restrict__ b,
    float* __restrict__ of, short* __restrict__ ob)
{
  const int idx = blockIdx.x * 256 + threadIdx.x;
  const float v = a[idx] + b[idx];
  of[idx] = v;
  if (ob) ob[idx] = f2bf(v);
}

// bf16 convert with optional add of second fp32 source (n = 65536 fixed grid)
__global__ __launch_bounds__(256) void cvt_bf(
    const float* __restrict__ src, const float* __restrict__ add,
    short* __restrict__ dst)
{
  const int idx = blockIdx.x * 256 + threadIdx.x;
  float v = src[idx];
  if (add) v += add[idx];
  dst[idx] = f2bf(v);
}

// log_softmax over rows of 10000
__global__ __launch_bounds__(256) void logsoftmax_k(
    const float* __restrict__ logits, float* __restrict__ out)
{
  const int b = blockIdx.x, t = threadIdx.x;
  const int lane = t & 63, wv = t >> 6;
  __shared__ float red[4];
  const float* p = logits + (size_t)b * NOUT;
  float m = -3.4e38f;
  for (int j = t; j < NOUT; j += 256) m = fmaxf(m, p[j]);
#pragma unroll
  for (int o = 32; o >= 1; o >>= 1) m = fmaxf(m, __shfl_xor(m, o));
  if (lane == 0) red[wv] = m;
  __syncthreads();
  m = fmaxf(fmaxf(red[0], red[1]), fmaxf(red[2], red[3]));
  float s = 0.f;
  for (int j = t; j < NOUT; j += 256) s += __expf(p[j] - m);
#pragma unroll
  for (int o = 32; o >= 1; o >>= 1) s += __shfl_xor(s, o);
  __syncthreads();
  if (lane == 0) red[wv] = s;
  __syncthreads();
  s = red[0] + red[1] + red[2] + red[3];
  const float lg = m + __logf(s);
  float* q = out + (size_t)b * NOUT;
  for (int j = t; j < NOUT; j += 256) q[j] = p[j] - lg;
}

extern "C" void kernel_launch(void* const* d_in, const int* in_sizes, int n_in,
                              void* d_out, int out_size, void* d_ws, size_t ws_size,
                              hipStream_t stream)
{
  const float* x      = (const float*)d_in[0];
  const float* att    = (const float*)d_in[1];
  const float* inp    = (const float*)d_in[2];
  const float* a2a_w  = (const float*)d_in[3];
  const float* a2a_b  = (const float*)d_in[4];
  const float* h2a_w  = (const float*)d_in[5];
  const float* h2a_b  = (const float*)d_in[6];
  const float* d2d_w  = (const float*)d_in[7];
  const float* a2a1_w = (const float*)d_in[9];
  const float* a2a1_b = (const float*)d_in[10];
  const float* h2a1_w = (const float*)d_in[11];
  const float* h2a1_b = (const float*)d_in[12];
  const float* d2d1_w = (const float*)d_in[13];
  const float* i2h_w  = (const float*)d_in[15];
  const float* i2h_b  = (const float*)d_in[16];
  const float* h2h_w  = (const float*)d_in[17];
  const float* h2h_b  = (const float*)d_in[18];
  const float* a2h_w  = (const float*)d_in[19];
  const float* a2h_b  = (const float*)d_in[20];
  const float* proj_w = (const float*)d_in[21];
  const float* proj_b = (const float*)d_in[22];
  float* out = (float*)d_out;

  const int S = NB * NA;     // 65536
  float* wsf = (float*)d_ws;
  float* hhA = wsf;                // [S] each
  float* hhB = hhA + S;
  float* hhC = hhB + S;
  float* hhD = hhC + S;
  float* scA = hhD + S;
  float* scB = scA + S;
  float* scC = scB + S;
  float* scD = scC + S;
  float* arA = scD + S;
  float* arB = arA + S;
  float* arC = arB + S;
  float* arD = arC + S;
  float* sums   = arD + S;               // 128*4096
  float* logits = sums + NB * 4096;      // 128*10000
  float* nh0f   = logits + (size_t)NB * NOUT;
  float* nh1f   = nh0f + S;
  short* sreg   = (short*)(nh1f + S);
  short* xt0b = sreg;
  short* xt1b = xt0b + S;
  short* ph0b = xt1b + S;
  short* ph1b = ph0b + S;
  short* arAb = ph1b + S;
  short* arBb = arAb + S;
  short* nh0b = arBb + S;
  short* nh1b = nh0b + S;
  short* th1b = nh1b + S;
  short* attB  = th1b + S;               // 128*512*512 bf16
  short* a2aWb = attB + (size_t)S * 512;
  short* h2aWb = a2aWb + NA * NR;
  short* a2a1Wb = h2aWb + NA * NR;
  short* h2a1Wb = a2a1Wb + NA * NR;
  short* i2hWb = h2a1Wb + NA * NR;       // [2][2][2048][512]
  short* h2hWb = i2hWb + (size_t)2 * 2 * 2048 * 512;
  short* a2hWb = h2hWb + (size_t)2 * 2 * 2048 * 512;
  short* projWb = a2hWb + (size_t)2 * 2 * 2048 * 512;  // 10000*512

  const float* prev_c0 = inp;
  const float* prev_h0 = inp + S;
  const float* prev_c1 = inp + 2 * S;
  const float* prev_h1 = inp + 3 * S;
  const size_t LSTRIDE_W = (size_t)2 * 2048 * 512;   // per-layer bf16 weight stride
  const size_t LSTRIDE_B = 4096;

  // zero the att_res accumulators (atomic targets)
  hipMemsetAsync(arA, 0, (size_t)4 * S * sizeof(float), stream);

  // -------- bf16 prepass: att + all weights --------
  cvt_f2b<<<(S * 512 / 8 + 255) / 256, 256, 0, stream>>>(att, attB, S * 512 / 8);
  cvt_f2b<<<(NA * NR / 8 + 255) / 256, 256, 0, stream>>>(a2a_w, a2aWb, NA * NR / 8);
  cvt_f2b<<<(NA * NR / 8 + 255) / 256, 256, 0, stream>>>(h2a_w, h2aWb, NA * NR / 8);
  cvt_f2b<<<(NA * NR / 8 + 255) / 256, 256, 0, stream>>>(a2a1_w, a2a1Wb, NA * NR / 8);
  cvt_f2b<<<(NA * NR / 8 + 255) / 256, 256, 0, stream>>>(h2a1_w, h2a1Wb, NA * NR / 8);
  const int WG8 = (int)(2 * LSTRIDE_W / 8);
  cvt_f2b<<<(WG8 + 255) / 256, 256, 0, stream>>>(i2h_w, i2hWb, WG8);
  cvt_f2b<<<(WG8 + 255) / 256, 256, 0, stream>>>(h2h_w, h2hWb, WG8);
  cvt_f2b<<<(WG8 + 255) / 256, 256, 0, stream>>>(a2h_w, a2hWb, WG8);
  cvt_f2b<<<(NOUT * NR / 8 + 255) / 256, 256, 0, stream>>>(proj_w, projWb, NOUT * NR / 8);

  // bf16 activations known up-front
  cvt_bf<<<256, 256, 0, stream>>>(x, nullptr, xt0b);
  cvt_bf<<<256, 256, 0, stream>>>(prev_h0, nullptr, ph0b);
  cvt_bf<<<256, 256, 0, stream>>>(prev_h1, nullptr, ph1b);

  // hh for the two set-0 attends (both h's known)
  gemm_tn512<<<dim3(2, 4), 256, 0, stream>>>(h2aWb, ph0b, h2a_b, hhA, 512, 511);
  gemm_tn512<<<dim3(2, 4), 256, 0, stream>>>(h2aWb, ph1b, h2a_b, hhB, 512, 511);

  // set-0 score GEMM, dual epilogue -> scores A (layer0 prev) + B (layer1 prev)
  score_pass<<<1024, 512, 0, stream>>>(attB, a2aWb, a2a_b, d2d_w, hhA, hhB, scA, scB);
  softmax512<<<256, 512, 0, stream>>>(scA);            // covers scA and scB
  att_res_pass<<<dim3(4, 128), 512, 0, stream>>>(attB, scA, scB, arA, arB);
  cvt_bf<<<256, 256, 0, stream>>>(arA, nullptr, arAb);
  cvt_bf<<<256, 256, 0, stream>>>(arB, nullptr, arBb);

  // ---- layer 0 LSTM ----
  gates_gemm<<<dim3(16, 4), 256, 0, stream>>>(
      i2hWb, h2hWb, a2hWb, xt0b, ph0b, arAb, i2h_b, h2h_b, a2h_b, sums);
  lstm_combine<<<256, 256, 0, stream>>>(sums, prev_c0, out /*next_c0*/, nh0f, nh0b);

  // attend set-1 on next_h0
  gemm_tn512<<<dim3(2, 4), 256, 0, stream>>>(h2a1Wb, nh0b, h2a1_b, hhC, 512, 511);
  score_pass<<<1024, 512, 0, stream>>>(attB, a2a1Wb, a2a1_b, d2d1_w, hhC, nullptr, scC, nullptr);
  softmax512<<<128, 512, 0, stream>>>(scC);
  att_res_pass<<<dim3(4, 128), 512, 0, stream>>>(attB, scC, nullptr, arC, nullptr);
  add_store<<<256, 256, 0, stream>>>(arC, nh0f, out + S /*top_h0*/, nullptr);
  cvt_bf<<<256, 256, 0, stream>>>(x, out + S, xt1b);   // xt1 = x + top_h0

  // ---- layer 1 LSTM ----
  gates_gemm<<<dim3(16, 4), 256, 0, stream>>>(
      i2hWb + LSTRIDE_W, h2hWb + LSTRIDE_W, a2hWb + LSTRIDE_W,
      xt1b, ph1b, arBb,
      i2h_b + LSTRIDE_B, h2h_b + LSTRIDE_B, a2h_b + LSTRIDE_B, sums);
  lstm_combine<<<256, 256, 0, stream>>>(sums, prev_c1, out + 2 * S /*next_c1*/, nh1f, nh1b);

  // attend set-1 on next_h1
  gemm_tn512<<<dim3(2, 4), 256, 0, stream>>>(h2a1Wb, nh1b, h2a1_b, hhD, 512, 511);
  score_pass<<<1024, 512, 0, stream>>>(attB, a2a1Wb, a2a1_b, d2d1_w, hhD, nullptr, scD, nullptr);
  softmax512<<<128, 512, 0, stream>>>(scD);
  att_res_pass<<<dim3(4, 128), 512, 0, stream>>>(attB, scD, nullptr, arD, nullptr);
  add_store<<<256, 256, 0, stream>>>(arD, nh1f, out + 3 * S /*top_h1*/, th1b);

  // projection + log_softmax
  gemm_tn512<<<dim3(40, 4), 256, 0, stream>>>(projWb, th1b, proj_b, logits, NOUT, NOUT - 1);
  logsoftmax_k<<<128, 256, 0, stream>>>(logits, out + 4 * S);
}

// Round 4
// 850.406 us; speedup vs baseline: 1.2576x; 1.2576x over previous
//
#include <hip/hip_runtime.h>
#include <hip/hip_bf16.h>

#define NB 128
#define NA 512
#define NR 512
#define NOUT 10000

typedef __attribute__((ext_vector_type(8))) short bf16x8;
typedef __attribute__((ext_vector_type(4))) float f32x4;

__device__ inline short f2bf(float f) {
  __hip_bfloat16 h = __float2bfloat16(f);
  return *reinterpret_cast<const short*>(&h);
}
__device__ inline float bf2f(short s) {
  unsigned u = (unsigned)(unsigned short)s << 16;
  return __uint_as_float(u);
}
__device__ inline float fast_tanh(float x) {
  float e = __expf(2.0f * x);
  return 1.0f - 2.0f / (e + 1.0f);
}
__device__ inline float fast_sigmoid(float x) {
  return 1.0f / (1.0f + __expf(-x));
}

// ---------------- bulk fp32->bf16 ----------------
__global__ __launch_bounds__(256) void cvt_f2b(
    const float* __restrict__ src, short* __restrict__ dst, int n8)
{
  const int i = blockIdx.x * 256 + threadIdx.x;
  if (i >= n8) return;
  f32x4 a = ((const f32x4*)src)[2 * i];
  f32x4 b = ((const f32x4*)src)[2 * i + 1];
  bf16x8 r;
  r[0] = f2bf(a[0]); r[1] = f2bf(a[1]); r[2] = f2bf(a[2]); r[3] = f2bf(a[3]);
  r[4] = f2bf(b[0]); r[5] = f2bf(b[1]); r[6] = f2bf(b[2]); r[7] = f2bf(b[3]);
  ((bf16x8*)dst)[i] = r;
}

// 4-segment cvt (uniform power-of-two n8 per segment, via shift)
__global__ __launch_bounds__(256) void cvt_multi(
    const float* __restrict__ s0, const float* __restrict__ s1,
    const float* __restrict__ s2, const float* __restrict__ s3,
    short* __restrict__ d0, short* __restrict__ d1,
    short* __restrict__ d2, short* __restrict__ d3, int sh)
{
  const int i = blockIdx.x * 256 + threadIdx.x;
  const int seg = i >> sh, j = i & ((1 << sh) - 1);
  const float* s = seg == 0 ? s0 : seg == 1 ? s1 : seg == 2 ? s2 : s3;
  short* d = seg == 0 ? d0 : seg == 1 ? d1 : seg == 2 ? d2 : d3;
  if (!s) return;
  f32x4 a = ((const f32x4*)s)[2 * j];
  f32x4 b = ((const f32x4*)s)[2 * j + 1];
  bf16x8 r;
  r[0] = f2bf(a[0]); r[1] = f2bf(a[1]); r[2] = f2bf(a[2]); r[3] = f2bf(a[3]);
  r[4] = f2bf(b[0]); r[5] = f2bf(b[1]); r[6] = f2bf(b[2]); r[7] = f2bf(b[3]);
  ((bf16x8*)d)[j] = r;
}

// ---------------------------------------------------------------------------
// gemm_v: C[i][j] = sum_k A[i][k]*Bw[j][k] + bias[j], bf16 out.
// A [65536][512], Bw [512][512]. Tile 128x128, BK=64, 4 waves (2x2),
// XOR-swizzled LDS (slot ^ (row&7)), XCD-chunked 1D grid (2048 blocks).
// ---------------------------------------------------------------------------
__global__ __launch_bounds__(256) void gemm_v(
    const short* __restrict__ A, const short* __restrict__ Bw,
    const float* __restrict__ bias, short* __restrict__ C)
{
  __shared__ short Als[128 * 64];
  __shared__ short Bls[128 * 64];
  const int tid = threadIdx.x;
  const int wv = tid >> 6, l = tid & 63;
  const int l15 = l & 15, l4 = l >> 4;
  const int bid = blockIdx.x;
  const int xcd = bid & 7, idx = bid >> 3;
  const int rt = xcd * 64 + (idx >> 2), cb = idx & 3;
  const int row0 = rt * 128, ncol0 = cb * 128;
  const int wm = wv >> 1, wn = wv & 1;
  const int sr_ = tid >> 1;          // staging row 0..127
  const int sb = (tid & 1) * 4;      // slot base (0 or 4)
  const int r7 = sr_ & 7;
  const short* gA = A + (size_t)(row0 + sr_) * 512 + sb * 8;
  const short* gB = Bw + (size_t)(ncol0 + sr_) * 512 + sb * 8;
  const int wbase = sr_ * 64;

  f32x4 acc[4][4] = {};

  for (int kk = 0; kk < 512; kk += 64) {
    bf16x8 ra[4], rb[4];
#pragma unroll
    for (int j = 0; j < 4; j++) {
      ra[j] = *(const bf16x8*)(gA + kk + j * 8);
      rb[j] = *(const bf16x8*)(gB + kk + j * 8);
    }
    __syncthreads();
#pragma unroll
    for (int j = 0; j < 4; j++) {
      const int sl = (sb + j) ^ r7;
      *(bf16x8*)(&Als[wbase + sl * 8]) = ra[j];
      *(bf16x8*)(&Bls[wbase + sl * 8]) = rb[j];
    }
    __syncthreads();
#pragma unroll
    for (int ks = 0; ks < 2; ks++) {
      bf16x8 af[4], bfr[4];
#pragma unroll
      for (int mf = 0; mf < 4; mf++) {
        const int row = wm * 64 + mf * 16 + l15;
        af[mf] = *(const bf16x8*)(&Als[row * 64 + ((ks * 4 + l4) ^ (row & 7)) * 8]);
      }
#pragma unroll
      for (int nf = 0; nf < 4; nf++) {
        const int row = wn * 64 + nf * 16 + l15;
        bfr[nf] = *(const bf16x8*)(&Bls[row * 64 + ((ks * 4 + l4) ^ (row & 7)) * 8]);
      }
#pragma unroll
      for (int mf = 0; mf < 4; mf++)
#pragma unroll
        for (int nf = 0; nf < 4; nf++)
          acc[mf][nf] = __builtin_amdgcn_mfma_f32_16x16x32_bf16(af[mf], bfr[nf], acc[mf][nf], 0, 0, 0);
    }
  }
#pragma unroll
  for (int mf = 0; mf < 4; mf++)
#pragma unroll
    for (int r2 = 0; r2 < 4; r2++) {
      const int grow = row0 + wm * 64 + mf * 16 + l4 * 4 + r2;
#pragma unroll
      for (int nf = 0; nf < 4; nf++) {
        const int gcol = ncol0 + wn * 64 + nf * 16 + l15;
        C[(size_t)grow * 512 + gcol] = f2bf(acc[mf][nf][r2] + bias[gcol]);
      }
    }
}

// ---------------------------------------------------------------------------
// attend_fused: per-b block (512 thr). scores = sum_k tanh(v[b,a,k]+hh[b,a])*wd[k]
// -> softmax over a -> ar[r] = sum_a att[b,a,r]*w[a] -> epilogues.
// ---------------------------------------------------------------------------
__global__ __launch_bounds__(512) void attend_fused(
    const short* __restrict__ v,     // [B*A][512] bf16 (incl. ba)
    const short* __restrict__ attb,  // [B*A][512] bf16
    const float* __restrict__ wd,    // [512]
    const float* __restrict__ hh1,   // [B*512]
    const float* __restrict__ hh2,   // null -> single variant
    const float* __restrict__ addin, // added to ar (variant1) for outf/outb
    const float* __restrict__ xadd,  // extra add for outb1 only
    float* __restrict__ outf1,
    short* __restrict__ outb1,
    short* __restrict__ outb2)
{
  __shared__ float hhl[2][512];
  __shared__ float wdl[512];
  __shared__ float scl[2][512];
  __shared__ float red8[2][8], red8b[2][8];
  __shared__ float redw[8][512];

  const int tid = threadIdx.x;
  const int l = tid & 63, wv = tid >> 6;
  const int b = blockIdx.x;
  const bool dual = (hh2 != nullptr);

  wdl[tid] = wd[tid];
  hhl[0][tid] = hh1[b * 512 + tid];
  if (dual) hhl[1][tid] = hh2[b * 512 + tid];
  __syncthreads();

  // ---- scores ----
#pragma unroll 1
  for (int rg = 0; rg < 8; rg++) {
    const int a = wv * 64 + rg * 8 + (l >> 3);
    const float hv1 = hhl[0][a];
    const float hv2 = dual ? hhl[1][a] : 0.f;
    float t1 = 0.f, t2 = 0.f;
    const short* vp = v + ((size_t)(b << 9) + a) * 512 + (l & 7) * 8;
#pragma unroll
    for (int j = 0; j < 8; j++) {
      bf16x8 vv = *(const bf16x8*)(vp + j * 64);
#pragma unroll
      for (int e = 0; e < 8; e++) {
        const float vf = bf2f(vv[e]);
        const float w = wdl[j * 64 + (l & 7) * 8 + e];
        t1 += fast_tanh(vf + hv1) * w;
        if (dual) t2 += fast_tanh(vf + hv2) * w;
      }
    }
    t1 += __shfl_xor(t1, 1); t1 += __shfl_xor(t1, 2); t1 += __shfl_xor(t1, 4);
    if (dual) { t2 += __shfl_xor(t2, 1); t2 += __shfl_xor(t2, 2); t2 += __shfl_xor(t2, 4); }
    if ((l & 7) == 0) { scl[0][a] = t1; if (dual) scl[1][a] = t2; }
  }
  __syncthreads();

  // ---- softmax (both variants) ----
  float x1 = scl[0][tid];
  float x2 = dual ? scl[1][tid] : 0.f;
  float m1 = x1, m2 = x2;
#pragma unroll
  for (int o = 32; o >= 1; o >>= 1) { m1 = fmaxf(m1, __shfl_xor(m1, o)); m2 = fmaxf(m2, __shfl_xor(m2, o)); }
  if (l == 0) { red8[0][wv] = m1; red8[1][wv] = m2; }
  __syncthreads();
  float gm1 = red8[0][0], gm2 = red8[1][0];
#pragma unroll
  for (int i = 1; i < 8; i++) { gm1 = fmaxf(gm1, red8[0][i]); gm2 = fmaxf(gm2, red8[1][i]); }
  const float e1 = __expf(x1 - gm1);
  const float e2 = dual ? __expf(x2 - gm2) : 0.f;
  float s1 = e1, s2 = e2;
#pragma unroll
  for (int o = 32; o >= 1; o >>= 1) { s1 += __shfl_xor(s1, o); s2 += __shfl_xor(s2, o); }
  if (l == 0) { red8b[0][wv] = s1; red8b[1][wv] = s2; }
  __syncthreads();
  float gs1 = 0.f, gs2 = 0.f;
#pragma unroll
  for (int i = 0; i < 8; i++) { gs1 += red8b[0][i]; gs2 += red8b[1][i]; }
  scl[0][tid] = e1 / gs1;
  if (dual) scl[1][tid] = e2 / gs2;
  __syncthreads();

  // ---- att_res ----
  float a1[8] = {0, 0, 0, 0, 0, 0, 0, 0};
  float a2[8] = {0, 0, 0, 0, 0, 0, 0, 0};
  const short* ap = attb + (size_t)(b << 9) * 512 + l * 8;
#pragma unroll 4
  for (int i = 0; i < 64; i++) {
    const int a = wv + i * 8;
    bf16x8 av = *(const bf16x8*)(ap + (size_t)a * 512);
    const float w1 = scl[0][a];
    const float w2 = dual ? scl[1][a] : 0.f;
#pragma unroll
    for (int e = 0; e < 8; e++) {
      const float f = bf2f(av[e]);
      a1[e] += f * w1;
      if (dual) a2[e] += f * w2;
    }
  }
  {
    f32x4 w0 = {a1[0], a1[1], a1[2], a1[3]};
    f32x4 w1v = {a1[4], a1[5], a1[6], a1[7]};
    *(f32x4*)(&redw[wv][l * 8]) = w0;
    *(f32x4*)(&redw[wv][l * 8 + 4]) = w1v;
  }
  __syncthreads();
  float ar = 0.f;
#pragma unroll
  for (int w = 0; w < 8; w++) ar += redw[w][tid];
  {
    const int gi = b * 512 + tid;
    const float val = ar + (addin ? addin[gi] : 0.f);
    if (outf1) outf1[gi] = val;
    if (outb1) outb1[gi] = f2bf(val + (xadd ? xadd[gi] : 0.f));
  }
  if (dual) {
    __syncthreads();
    f32x4 w0 = {a2[0], a2[1], a2[2], a2[3]};
    f32x4 w1v = {a2[4], a2[5], a2[6], a2[7]};
    *(f32x4*)(&redw[wv][l * 8]) = w0;
    *(f32x4*)(&redw[wv][l * 8 + 4]) = w1v;
    __syncthreads();
    float ar2 = 0.f;
#pragma unroll
    for (int w = 0; w < 8; w++) ar2 += redw[w][tid];
    outb2[b * 512 + tid] = f2bf(ar2);
  }
}

// ---------------------------------------------------------------------------
// 1-wave small GEMM: outh[n*512+m] = sum_k Wb[m][k]*Hb[n][k] + bias[m]
// grid (M/64, N/32), 64 threads.
// ---------------------------------------------------------------------------
__global__ __launch_bounds__(64) void gemm_hh(
    const short* __restrict__ Wb, const short* __restrict__ Hb,
    const float* __restrict__ bias, float* __restrict__ outh)
{
  const int l = threadIdx.x, l15 = l & 15, l4 = l >> 4;
  const int m0 = blockIdx.x * 64, n0 = blockIdx.y * 32;
  f32x4 acc[4][2] = {};
#pragma unroll 2
  for (int kk = 0; kk < 512; kk += 32) {
    bf16x8 af[4], bfr[2];
#pragma unroll
    for (int mf = 0; mf < 4; mf++)
      af[mf] = *(const bf16x8*)(Wb + (size_t)(m0 + mf * 16 + l15) * 512 + kk + l4 * 8);
#pragma unroll
    for (int nf = 0; nf < 2; nf++)
      bfr[nf] = *(const bf16x8*)(Hb + (size_t)(n0 + nf * 16 + l15) * 512 + kk + l4 * 8);
#pragma unroll
    for (int mf = 0; mf < 4; mf++)
#pragma unroll
      for (int nf = 0; nf < 2; nf++)
        acc[mf][nf] = __builtin_amdgcn_mfma_f32_16x16x32_bf16(af[mf], bfr[nf], acc[mf][nf], 0, 0, 0);
  }
#pragma unroll
  for (int mf = 0; mf < 4; mf++)
#pragma unroll
    for (int r2 = 0; r2 < 4; r2++) {
      const int row = m0 + mf * 16 + l4 * 4 + r2;
      const float bv = bias[row];
#pragma unroll
      for (int nf = 0; nf < 2; nf++)
        outh[(size_t)(n0 + nf * 16 + l15) * 512 + row] = acc[mf][nf][r2] + bv;
    }
}

// ---------------------------------------------------------------------------
// gates GEMM: M=4096 rows (p*2048+g), N=128, K=3x512, XCD-chunked 64 blocks.
// ---------------------------------------------------------------------------
__global__ __launch_bounds__(256) void gates_gemm(
    const short* __restrict__ A1, const short* __restrict__ A2, const short* __restrict__ A3,
    const short* __restrict__ B1, const short* __restrict__ B2, const short* __restrict__ B3,
    const float* __restrict__ b1, const float* __restrict__ b2, const float* __restrict__ b3,
    float* __restrict__ out)
{
  const int tid = threadIdx.x;
  const int wv = tid >> 6, lane = tid & 63;
  const int l15 = lane & 15, l4 = lane >> 4;
  const int bid = blockIdx.x;
  const int xcd = bid & 7, i2 = bid >> 3;
  const int mrow0 = (xcd * 2 + (i2 >> 2)) * 256 + wv * 64;
  const int ncol0 = (i2 & 3) * 32;
  f32x4 acc[4][2] = {};
#pragma unroll 1
  for (int seg = 0; seg < 3; seg++) {
    const short* As = seg == 0 ? A1 : (seg == 1 ? A2 : A3);
    const short* Bs = seg == 0 ? B1 : (seg == 1 ? B2 : B3);
    for (int kk = 0; kk < 512; kk += 32) {
      bf16x8 afr[4];
#pragma unroll
      for (int mf = 0; mf < 4; mf++)
        afr[mf] = *(const bf16x8*)(As + (size_t)(mrow0 + mf * 16 + l15) * 512 + kk + l4 * 8);
      bf16x8 bfr[2];
#pragma unroll
      for (int nf = 0; nf < 2; nf++)
        bfr[nf] = *(const bf16x8*)(Bs + (size_t)(ncol0 + nf * 16 + l15) * 512 + kk + l4 * 8);
#pragma unroll
      for (int mf = 0; mf < 4; mf++)
#pragma unroll
        for (int nf = 0; nf < 2; nf++)
          acc[mf][nf] = __builtin_amdgcn_mfma_f32_16x16x32_bf16(afr[mf], bfr[nf], acc[mf][nf], 0, 0, 0);
    }
  }
#pragma unroll
  for (int mf = 0; mf < 4; mf++)
#pragma unroll
    for (int r = 0; r < 4; r++) {
      const int row = mrow0 + mf * 16 + l4 * 4 + r;
      const float bv = b1[row] + b2[row] + b3[row];
#pragma unroll
      for (int nf = 0; nf < 2; nf++) {
        const int col = ncol0 + nf * 16 + l15;
        out[(size_t)col * 4096 + row] = acc[mf][nf][r] + bv;
      }
    }
}

// generic TN GEMM for projection (A bf16 [M][512], B bf16 [N][512])
__global__ __launch_bounds__(256) void gemm_tn512(
    const short* __restrict__ Ab, const short* __restrict__ Bb,
    const float* __restrict__ bias, float* __restrict__ out,
    const int M, const int Mclamp)
{
  const int tid = threadIdx.x;
  const int wv = tid >> 6, lane = tid & 63;
  const int l15 = lane & 15, l4 = lane >> 4;
  const int mrow0 = blockIdx.x * 256 + wv * 64;
  const int ncol0 = blockIdx.y * 32;
  f32x4 acc[4][2] = {};
  for (int kk = 0; kk < 512; kk += 32) {
    bf16x8 afr[4];
#pragma unroll
    for (int mf = 0; mf < 4; mf++) {
      int row = mrow0 + mf * 16 + l15;
      row = row > Mclamp ? Mclamp : row;
      afr[mf] = *(const bf16x8*)(Ab + (size_t)row * 512 + kk + l4 * 8);
    }
    bf16x8 bfr[2];
#pragma unroll
    for (int nf = 0; nf < 2; nf++)
      bfr[nf] = *(const bf16x8*)(Bb + (size_t)(ncol0 + nf * 16 + l15) * 512 + kk + l4 * 8);
#pragma unroll
    for (int mf = 0; mf < 4; mf++)
#pragma unroll
      for (int nf = 0; nf < 2; nf++)
        acc[mf][nf] = __builtin_amdgcn_mfma_f32_16x16x32_bf16(afr[mf], bfr[nf], acc[mf][nf], 0, 0, 0);
  }
#pragma unroll
  for (int mf = 0; mf < 4; mf++)
#pragma unroll
    for (int r = 0; r < 4; r++) {
      const int row = mrow0 + mf * 16 + l4 * 4 + r;
      if (row < M) {
        const float bv = bias ? bias[row] : 0.f;
#pragma unroll
        for (int nf = 0; nf < 2; nf++) {
          const int col = ncol0 + nf * 16 + l15;
          out[(size_t)col * M + row] = acc[mf][nf][r] + bv;
        }
      }
    }
}

// gate nonlinearities + per-p LSTM cell + mean over P
__global__ __launch_bounds__(256) void lstm_combine(
    const float* __restrict__ sums, const float* __restrict__ prev_c,
    float* __restrict__ out_c, float* __restrict__ nh_f, short* __restrict__ nh_bf)
{
  const int idx = blockIdx.x * 256 + threadIdx.x;
  const int b = idx >> 9, r = idx & 511;
  const float* sb = sums + (size_t)b * 4096;
  const float pc = prev_c[idx];
  float nc = 0.f, nh = 0.f;
#pragma unroll
  for (int p = 0; p < 2; p++) {
    const float si = sb[p * 2048 + r];
    const float sf = sb[p * 2048 + 512 + r];
    const float so = sb[p * 2048 + 1024 + r];
    const float st = sb[p * 2048 + 1536 + r];
    const float ig = fast_sigmoid(si), fg = fast_sigmoid(sf), og = fast_sigmoid(so);
    const float it = fast_tanh(st);
    const float c = fg * pc + ig * it;
    const float h = og * fast_tanh(c);
    nc += c; nh += h;
  }
  nc *= 0.5f; nh *= 0.5f;
  out_c[idx] = nc;
  nh_f[idx] = nh;
  nh_bf[idx] = f2bf(nh);
}

// log_softmax over rows of 10000
__global__ __launch_bounds__(256) void logsoftmax_k(
    const float* __restrict__ logits, float* __restrict__ out)
{
  const int b = blockIdx.x, t = threadIdx.x;
  const int lane = t & 63, wv = t >> 6;
  __shared__ float red[4];
  const float* p = logits + (size_t)b * NOUT;
  float m = -3.4e38f;
  for (int j = t; j < NOUT; j += 256) m = fmaxf(m, p[j]);
#pragma unroll
  for (int o = 32; o >= 1; o >>= 1) m = fmaxf(m, __shfl_xor(m, o));
  if (lane == 0) red[wv] = m;
  __syncthreads();
  m = fmaxf(fmaxf(red[0], red[1]), fmaxf(red[2], red[3]));
  float s = 0.f;
  for (int j = t; j < NOUT; j += 256) s += __expf(p[j] - m);
#pragma unroll
  for (int o = 32; o >= 1; o >>= 1) s += __shfl_xor(s, o);
  __syncthreads();
  if (lane == 0) red[wv] = s;
  __syncthreads();
  s = red[0] + red[1] + red[2] + red[3];
  const float lg = m + __logf(s);
  float* q = out + (size_t)b * NOUT;
  for (int j = t; j < NOUT; j += 256) q[j] = p[j] - lg;
}

extern "C" void kernel_launch(void* const* d_in, const int* in_sizes, int n_in,
                              void* d_out, int out_size, void* d_ws, size_t ws_size,
                              hipStream_t stream)
{
  const float* x      = (const float*)d_in[0];
  const float* att    = (const float*)d_in[1];
  const float* inp    = (const float*)d_in[2];
  const float* a2a_w  = (const float*)d_in[3];
  const float* a2a_b  = (const float*)d_in[4];
  const float* h2a_w  = (const float*)d_in[5];
  const float* h2a_b  = (const float*)d_in[6];
  const float* d2d_w  = (const float*)d_in[7];
  const float* a2a1_w = (const float*)d_in[9];
  const float* a2a1_b = (const float*)d_in[10];
  const float* h2a1_w = (const float*)d_in[11];
  const float* h2a1_b = (const float*)d_in[12];
  const float* d2d1_w = (const float*)d_in[13];
  const float* i2h_w  = (const float*)d_in[15];
  const float* i2h_b  = (const float*)d_in[16];
  const float* h2h_w  = (const float*)d_in[17];
  const float* h2h_b  = (const float*)d_in[18];
  const float* a2h_w  = (const float*)d_in[19];
  const float* a2h_b  = (const float*)d_in[20];
  const float* proj_w = (const float*)d_in[21];
  const float* proj_b = (const float*)d_in[22];
  float* out = (float*)d_out;

  const int S = NB * NA;                       // 65536
  const size_t SV = (size_t)S * 512;           // 33.55M
  const size_t WGL = (size_t)2 * 2 * 2048 * 512; // gates weights elems (both layers)
  const size_t LSTRIDE_W = (size_t)2 * 2048 * 512;
  const size_t LSTRIDE_B = 4096;

  short* attB  = (short*)d_ws;
  short* vbuf  = attB + SV;
  short* a2aWb = vbuf + SV;
  short* h2aWb = a2aWb + NA * NR;
  short* a2a1Wb = h2aWb + NA * NR;
  short* h2a1Wb = a2a1Wb + NA * NR;
  short* i2hWb = h2a1Wb + NA * NR;
  short* h2hWb = i2hWb + WGL;
  short* a2hWb = h2hWb + WGL;
  short* projWb = a2hWb + WGL;                 // 10000*512
  short* xt0b  = projWb + (size_t)NOUT * NR;
  short* xt1b  = xt0b + S;
  short* ph0b  = xt1b + S;                     // ph0b/ph1b contiguous (N=256 GEMM)
  short* ph1b  = ph0b + S;
  short* arAb  = ph1b + S;
  short* arBb  = arAb + S;
  short* nh0b  = arBb + S;
  short* nh1b  = nh0b + S;
  short* th1b  = nh1b + S;
  float* wsf   = (float*)(th1b + S);
  float* hhA   = wsf;                          // hhA/hhB contiguous
  float* hhB   = hhA + S;
  float* hhC   = hhB + S;
  float* hhD   = hhC + S;
  float* nh0f  = hhD + S;
  float* nh1f  = nh0f + S;
  float* sums  = nh1f + S;                     // 128*4096
  float* logits = sums + NB * 4096;            // 128*10000

  const float* prev_c0 = inp;
  const float* prev_h0 = inp + S;
  const float* prev_c1 = inp + 2 * S;
  const float* prev_h1 = inp + 3 * S;

  // -------- prepass: bf16 conversions --------
  cvt_multi<<<512, 256, 0, stream>>>(a2a_w, h2a_w, a2a1_w, h2a1_w,
                                     a2aWb, h2aWb, a2a1Wb, h2a1Wb, 15); // 4*32768
  cvt_f2b<<<(int)(WGL / 8 / 256), 256, 0, stream>>>(i2h_w, i2hWb, (int)(WGL / 8));
  cvt_f2b<<<(int)(WGL / 8 / 256), 256, 0, stream>>>(h2h_w, h2hWb, (int)(WGL / 8));
  cvt_f2b<<<(int)(WGL / 8 / 256), 256, 0, stream>>>(a2h_w, a2hWb, (int)(WGL / 8));
  cvt_f2b<<<(NOUT * NR / 8 + 255) / 256, 256, 0, stream>>>(proj_w, projWb, NOUT * NR / 8);
  cvt_f2b<<<(int)(SV / 8 / 256), 256, 0, stream>>>(att, attB, (int)(SV / 8));
  cvt_multi<<<96, 256, 0, stream>>>(x, prev_h0, prev_h1, nullptr,
                                    xt0b, ph0b, ph1b, nullptr, 13);     // 3*8192

  // -------- set-0 attend --------
  gemm_v<<<2048, 256, 0, stream>>>(attB, a2aWb, a2a_b, vbuf);
  gemm_hh<<<dim3(8, 8), 64, 0, stream>>>(h2aWb, ph0b, h2a_b, hhA);      // hhA+hhB (N=256)
  attend_fused<<<128, 512, 0, stream>>>(vbuf, attB, d2d_w, hhA, hhB,
                                        nullptr, nullptr, nullptr, arAb, arBb);

  // ---- layer 0 LSTM ----
  gates_gemm<<<64, 256, 0, stream>>>(i2hWb, h2hWb, a2hWb, xt0b, ph0b, arAb,
                                     i2h_b, h2h_b, a2h_b, sums);
  lstm_combine<<<256, 256, 0, stream>>>(sums, prev_c0, out /*next_c0*/, nh0f, nh0b);

  // -------- set-1 v (reuse vbuf; set-0 v is dead) --------
  gemm_v<<<2048, 256, 0, stream>>>(attB, a2a1Wb, a2a1_b, vbuf);

  // attend set-1 on next_h0 -> top_h0, xt1
  gemm_hh<<<dim3(8, 2), 64, 0, stream>>>(h2a1Wb, nh0b, h2a1_b, hhC);
  attend_fused<<<128, 512, 0, stream>>>(vbuf, attB, d2d1_w, hhC, nullptr,
                                        nh0f, x, out + S /*top_h0*/, xt1b, nullptr);

  // ---- layer 1 LSTM ----
  gates_gemm<<<64, 256, 0, stream>>>(i2hWb + LSTRIDE_W, h2hWb + LSTRIDE_W, a2hWb + LSTRIDE_W,
                                     xt1b, ph1b, arBb,
                                     i2h_b + LSTRIDE_B, h2h_b + LSTRIDE_B, a2h_b + LSTRIDE_B, sums);
  lstm_combine<<<256, 256, 0, stream>>>(sums, prev_c1, out + 2 * S /*next_c1*/, nh1f, nh1b);

  // attend set-1 on next_h1 -> top_h1
  gemm_hh<<<dim3(8, 2), 64, 0, stream>>>(h2a1Wb, nh1b, h2a1_b, hhD);
  attend_fused<<<128, 512, 0, stream>>>(vbuf, attB, d2d1_w, hhD, nullptr,
                                        nh1f, nullptr, out + 3 * S /*top_h1*/, th1b, nullptr);

  // projection + log_softmax
  gemm_tn512<<<dim3(40, 4), 256, 0, stream>>>(projWb, th1b, proj_b, logits, NOUT, NOUT - 1);
  logsoftmax_k<<<128, 256, 0, stream>>>(logits, out + 4 * S);
}